// Round 1
// baseline (8401.299 us; speedup 1.0000x reference)
//
#include <hip/hip_runtime.h>
#include <math.h>

// ---------------------------------------------------------------------------
// VectorQuantizer3D — R9: argmin GEMM moved from fp32 VALU (76 TF, 48% of
// vector peak) to bf16-split MFMA (3 products, fp32 accum), with bit-exact
// fallback to the R6 numerics on "fragile" rows (fp32-rounding-boundary
// proximity) so the argmin inherits R6's empirical pass record.
// ---------------------------------------------------------------------------

#define N_E    4096
#define EDIM   256
#define SPAT   8192
#define NROWS  16384
#define ZELEMS 4194304
#define NCHUNK 32        // code chunks of 128
#define NLOSSPARTS 16384

// Output offsets (flat float32 in return order)
#define OFF_LOSS    0
#define OFF_ZQ      1
#define OFF_PERP    4194305
#define OFF_ONEHOT  4194306
#define OFF_IDX     71303170
#define OFF_ZOUT    71319554
#define OFF_EMA     75513858

// Scratch carved out of output regions that are fully rewritten later:
//  - zh/zl/wh/wl live in out_onehot (combine_kernel rewrites every row after
//    argmin_kernel is done reading them). 16-byte aligned offsets.
//  - bD/bI partials live in out_z (outputs_kernel rewrites it after combine).
#define SCR_ZH  4194308
#define SCR_ZL  6291460
#define SCR_WH  8388612
#define SCR_WL  8912900
#define SCR_BD  71319554
#define SCR_BI  71843842

#define NEAR_M  6.2e-5f   // 2 ulp at |d|<512 — min-region margin
#define EB      2e-7f     // boundary-fragility bound (~33 sigma of split err)

typedef unsigned short u16;
typedef short short8 __attribute__((ext_vector_type(8)));
typedef float f32x4 __attribute__((ext_vector_type(4)));
typedef const void __attribute__((address_space(1)))* gas1;
typedef void __attribute__((address_space(3)))* las3;
#define GLOAD16(g, l) __builtin_amdgcn_global_load_lds((gas1)(g), (las3)(l), 16, 0, 0)

__device__ __forceinline__ u16 f2bf(float f) {   // RTNE fp32 -> bf16
    unsigned u = __float_as_uint(f);
    return (u16)((u + 0x7fffu + ((u >> 16) & 1u)) >> 16);
}
__device__ __forceinline__ float bf2f(u16 h) {
    return __uint_as_float(((unsigned)h) << 16);
}

// ---------------------------------------------------------------------------
// K0a: se[c] = sum_k W[c][k]^2 — VERBATIM R6 numerics (bit-match required).
// Also clears the fragile-row counter (runs before combine_kernel).
// ---------------------------------------------------------------------------
__global__ __launch_bounds__(256) void se_kernel(const float* __restrict__ W,
                                                 float* __restrict__ se,
                                                 int* __restrict__ cnt) {
    if (blockIdx.x == 0 && threadIdx.x == 0) *cnt = 0;
    int wid  = (blockIdx.x * 256 + threadIdx.x) >> 6;
    int lane = threadIdx.x & 63;
    if (wid < N_E) {
        const float4 v = *(const float4*)(W + (size_t)wid * EDIM + lane * 4);
        float s = v.x * v.x + v.y * v.y + v.z * v.z + v.w * v.w;
        #pragma unroll
        for (int off = 32; off > 0; off >>= 1) s += __shfl_down(s, off);
        if (lane == 0) se[wid] = s;
    }
}

// ---------------------------------------------------------------------------
// K0b: sz[row] = ||z_row||^2 — replicates R6's exact summation order:
// 4 chunks of 64 serial (ascending k), combined ((s0+s1)+s2)+s3.
// ---------------------------------------------------------------------------
__global__ __launch_bounds__(512) void rnorm_kernel(const float* __restrict__ z,
                                                    float* __restrict__ sz) {
    const int r0 = blockIdx.x * 128;
    const int bb = r0 >> 13;
    const int sp0 = r0 & (SPAT - 1);
    const float* zb = z + (size_t)bb * (EDIM * SPAT) + sp0;
    __shared__ float szp[4][128];
    const int lr = threadIdx.x & 127, kq = threadIdx.x >> 7;
    float s = 0.f;
    const float* p = zb + lr + (size_t)(kq * 64) * SPAT;
    for (int k = 0; k < 64; ++k) {
        float v = p[(size_t)k * SPAT];
        s += v * v;
    }
    szp[kq][lr] = s;
    __syncthreads();
    if (threadIdx.x < 128)
        sz[r0 + threadIdx.x] =
            ((szp[0][threadIdx.x] + szp[1][threadIdx.x]) + szp[2][threadIdx.x]) + szp[3][threadIdx.x];
}

// ---------------------------------------------------------------------------
// K0c: W -> bf16 hi/lo split, row-major [4096][256].
// ---------------------------------------------------------------------------
__global__ __launch_bounds__(256) void split_w_kernel(const float* __restrict__ W,
                                                      u16* __restrict__ wh,
                                                      u16* __restrict__ wl) {
    const size_t t = (size_t)blockIdx.x * 256 + threadIdx.x;   // 0..262143
    const float4 v = *(const float4*)(W + t * 4);
    u16 h0 = f2bf(v.x), h1 = f2bf(v.y), h2 = f2bf(v.z), h3 = f2bf(v.w);
    u16 l0 = f2bf(v.x - bf2f(h0)), l1 = f2bf(v.y - bf2f(h1));
    u16 l2 = f2bf(v.z - bf2f(h2)), l3 = f2bf(v.w - bf2f(h3));
    uint2 hp, lp;
    hp.x = (unsigned)h0 | ((unsigned)h1 << 16); hp.y = (unsigned)h2 | ((unsigned)h3 << 16);
    lp.x = (unsigned)l0 | ((unsigned)l1 << 16); lp.y = (unsigned)l2 | ((unsigned)l3 << 16);
    *(uint2*)(wh + t * 4) = hp;
    *(uint2*)(wl + t * 4) = lp;
}

// ---------------------------------------------------------------------------
// K0d: z [2][256][8192] -> transposed bf16 hi/lo [16384 rows][256 k].
// LDS tile transpose 64sp x 128c; 256-B coalesced reads and writes.
// ---------------------------------------------------------------------------
__global__ __launch_bounds__(256) void split_z_kernel(const float* __restrict__ z,
                                                      u16* __restrict__ zh,
                                                      u16* __restrict__ zl) {
    __shared__ float t[128][65];
    const int tid = threadIdx.x, wid = tid >> 6, lane = tid & 63;
    const int sp0 = blockIdx.x * 64, c0 = blockIdx.y * 128, b = blockIdx.z;
    const float* zb = z + (size_t)b * (EDIM * SPAT);
    #pragma unroll
    for (int it = 0; it < 32; ++it) {
        const int cl = wid + 4 * it;                 // 0..127
        t[cl][lane] = zb[(size_t)(c0 + cl) * SPAT + sp0 + lane];
    }
    __syncthreads();
    #pragma unroll
    for (int it = 0; it < 16; ++it) {
        const int r = wid + 4 * it;                  // 0..63
        const float v0 = t[2 * lane][r], v1 = t[2 * lane + 1][r];
        const u16 h0 = f2bf(v0), h1 = f2bf(v1);
        const u16 l0 = f2bf(v0 - bf2f(h0)), l1 = f2bf(v1 - bf2f(h1));
        const size_t row = (size_t)b * SPAT + sp0 + r;
        ((unsigned*)zh)[row * 128 + (c0 >> 1) + lane] = (unsigned)h0 | ((unsigned)h1 << 16);
        ((unsigned*)zl)[row * 128 + (c0 >> 1) + lane] = (unsigned)l0 | ((unsigned)l1 << 16);
    }
}

// ---------------------------------------------------------------------------
// K1: MFMA argmin. 128 rows x 128 codes per block, BK=32, 4 waves (2Mx2N),
// wave tile 64x64 = 4x4 16x16x32 frags, 3 MFMAs per frag (zh*wh+zh*wl+zl*wh).
// LDS rows hold [hi 32k | lo 32k] = 128 B with XOR chunk swizzle (2-way, free);
// staged via global_load_lds w=16 from pre-swizzled per-lane sources (G21).
// Epilogue: q = fl(fl(szr+se) - 2*acc)  (exact R6 expression), quantized
// first-index argmin, plus fp64 boundary-fragility flag for the fixup.
// MFMA orientation: mfma(a=W-frag, b=Z-frag): D rows(reg axis)=codes,
// cols(lane&15)=z-rows  (m89 C/D layout; attn "swapped-QK^T" evidence).
// ---------------------------------------------------------------------------
__global__ __launch_bounds__(256, 3) void argmin_kernel(
        const u16* __restrict__ zh, const u16* __restrict__ zl,
        const u16* __restrict__ wh, const u16* __restrict__ wl,
        const float* __restrict__ se, const float* __restrict__ sz,
        float* __restrict__ bD, int* __restrict__ bI) {
    __shared__ u16 sW[128][64];     // 16 KB: [code][hi32|lo32]
    __shared__ u16 sZ[128][64];     // 16 KB: [row ][hi32|lo32]
    __shared__ float mD[2][128];
    __shared__ int   mI[2][128];

    const int tid = threadIdx.x;
    const int wid = tid >> 6, lane = tid & 63;
    const int wm = wid >> 1, wn = wid & 1;
    const int lq = lane >> 4, lr = lane & 15;
    const int chunk = blockIdx.x;          // 0..31
    const int rbase = blockIdx.y * 128;
    const int cbase = chunk * 128;

    // staging: 2048 16-B chunks (1024 sW + 1024 sZ), 8 per thread.
    // LDS chunk o -> (row=o>>3, pos g=o&7); data there must be unswizzled
    // chunk u = g ^ (row&7); u<4 -> hi, else lo; k-offset (u&3)*8.
    const u16* gw[4]; const u16* gz[4];
    #pragma unroll
    for (int i = 0; i < 4; ++i) {
        const int o = i * 256 + tid;
        const int row = o >> 3, g = o & 7, u = g ^ (row & 7);
        const int ks = (u & 3) * 8;
        gw[i] = (u < 4 ? wh : wl) + (size_t)(cbase + row) * EDIM + ks;
        gz[i] = (u < 4 ? zh : zl) + (size_t)(rbase + row) * EDIM + ks;
    }

    // fragment LDS byte offsets (stage-invariant): row*128 + swz_chunk*16
    int aoff[4][2], boff[4][2];
    #pragma unroll
    for (int tt = 0; tt < 4; ++tt) {
        const int cl = wn * 64 + tt * 16 + lr;
        const int s0 = lq ^ (cl & 7);
        aoff[tt][0] = cl * 128 + s0 * 16;
        aoff[tt][1] = cl * 128 + (s0 ^ 4) * 16;
        const int rl = wm * 64 + tt * 16 + lr;
        const int s1 = lq ^ (rl & 7);
        boff[tt][0] = rl * 128 + s1 * 16;
        boff[tt][1] = rl * 128 + (s1 ^ 4) * 16;
    }

    f32x4 acc[4][4];
    #pragma unroll
    for (int ci = 0; ci < 4; ++ci)
        #pragma unroll
        for (int rj = 0; rj < 4; ++rj) {
            f32x4 zzz = {0.f, 0.f, 0.f, 0.f};
            acc[ci][rj] = zzz;
        }

    const char* sWb = (const char*)&sW[0][0];
    const char* sZb = (const char*)&sZ[0][0];

    for (int k0 = 0; k0 < 8; ++k0) {
        __syncthreads();                               // prev frag reads done
        #pragma unroll
        for (int i = 0; i < 4; ++i) {
            GLOAD16(gw[i], (char*)&sW[0][0] + (i * 256 + wid * 64) * 16);
            GLOAD16(gz[i], (char*)&sZ[0][0] + (i * 256 + wid * 64) * 16);
            gw[i] += 32; gz[i] += 32;
        }
        __syncthreads();                               // vmcnt(0) drain -> LDS valid

        short8 zbh[4], zbl[4];
        #pragma unroll
        for (int rj = 0; rj < 4; ++rj) {
            zbh[rj] = *(const short8*)(sZb + boff[rj][0]);
            zbl[rj] = *(const short8*)(sZb + boff[rj][1]);
        }
        #pragma unroll
        for (int ci = 0; ci < 4; ++ci) {
            const short8 wah = *(const short8*)(sWb + aoff[ci][0]);
            const short8 wal = *(const short8*)(sWb + aoff[ci][1]);
            #pragma unroll
            for (int rj = 0; rj < 4; ++rj) {
                acc[ci][rj] = __builtin_amdgcn_mfma_f32_16x16x32_bf16(wah, zbh[rj], acc[ci][rj], 0, 0, 0);
                acc[ci][rj] = __builtin_amdgcn_mfma_f32_16x16x32_bf16(wah, zbl[rj], acc[ci][rj], 0, 0, 0);
                acc[ci][rj] = __builtin_amdgcn_mfma_f32_16x16x32_bf16(wal, zbh[rj], acc[ci][rj], 0, 0, 0);
            }
        }
    }

    // ---- epilogue: quantized argmin + fragility flag ----
    f32x4 sev[4];
    #pragma unroll
    for (int ci = 0; ci < 4; ++ci)
        sev[ci] = *(const f32x4*)(se + cbase + wn * 64 + ci * 16 + lq * 4);

    #pragma unroll
    for (int rj = 0; rj < 4; ++rj) {
        const int rloc = wm * 64 + rj * 16 + lr;
        const float szr = sz[rbase + rloc];
        float b1 = 3.4e38f; int bi1 = 0; int fr = 0;
        #pragma unroll
        for (int ci = 0; ci < 4; ++ci) {
            #pragma unroll
            for (int r = 0; r < 4; ++r) {
                const float t1 = szr + sev[ci][r];
                const float m2 = 2.0f * acc[ci][rj][r];   // *2 exact
                const float q  = t1 - m2;                  // == R6's fl(t1-2m) bitwise
                const double dd = (double)t1 - (double)m2;
                const float rres = (float)(dd - (double)q);
                const float uq = __uint_as_float(__float_as_uint(q) & 0x7f800000u) * 1.1920929e-7f;
                if ((q < b1 + NEAR_M) && (0.5f * uq - fabsf(rres) < EB)) fr = 1;
                if (q < b1) { b1 = q; bi1 = cbase + wn * 64 + ci * 16 + lq * 4 + r; }
            }
        }
        #pragma unroll
        for (int mask = 16; mask <= 32; mask <<= 1) {
            const float od = __shfl_xor(b1, mask);
            const int   oi = __shfl_xor(bi1, mask);
            fr |= __shfl_xor(fr, mask);
            if (od < b1 || (od == b1 && oi < bi1)) { b1 = od; bi1 = oi; }
        }
        if (lq == 0) {
            mD[wn][rloc] = b1;
            mI[wn][rloc] = bi1 | (fr << 30);
        }
    }
    __syncthreads();
    if (tid < 128) {
        const float d0 = mD[0][tid], d1 = mD[1][tid];
        const int v0 = mI[0][tid], v1 = mI[1][tid];
        const int f = ((v0 | v1) >> 30) & 1;
        const int i0 = v0 & 0xFFFF, i1 = v1 & 0xFFFF;
        float dm; int im;
        if (d1 < d0 || (d1 == d0 && i1 < i0)) { dm = d1; im = i1; }
        else                                  { dm = d0; im = i0; }
        bD[(size_t)chunk * NROWS + rbase + tid] = dm;
        bI[(size_t)chunk * NROWS + rbase + tid] = im | (f << 30);
    }
}

// ---------------------------------------------------------------------------
// K1b: combine 32 chunk-partials per row (lane-parallel butterfly), write
// idx + onehot, append fragile rows to the fixup list.
// ---------------------------------------------------------------------------
__global__ __launch_bounds__(256) void combine_kernel(
        const float* __restrict__ bD, const int* __restrict__ bI,
        int* __restrict__ idx_ws, float* __restrict__ out_idx,
        float* __restrict__ out_onehot, int* __restrict__ cnt,
        int* __restrict__ list) {
    const int g = blockIdx.x * 256 + threadIdx.x;
    const int row = g >> 6, lane = g & 63, c = lane & 31;
    float d = bD[(size_t)c * NROWS + row];
    int v = bI[(size_t)c * NROWS + row];
    int fr = (v >> 30) & 1;
    int ii = v & 0xFFFF;
    #pragma unroll
    for (int mask = 16; mask > 0; mask >>= 1) {
        const float od = __shfl_xor(d, mask);
        const int oi = __shfl_xor(ii, mask);
        fr |= __shfl_xor(fr, mask);
        if (od < d || (od == d && oi < ii)) { d = od; ii = oi; }
    }
    if (lane == 0) {
        idx_ws[row]  = ii;
        out_idx[row] = (float)ii;
        if (fr) {
            const int p = atomicAdd(cnt, 1);
            if (p < NROWS) list[p] = row;
        }
    }
    float* dst = out_onehot + (size_t)row * N_E;
    #pragma unroll
    for (int w = 0; w < 16; ++w) {
        const int cb = w * 256 + lane * 4;
        float4 o;
        o.x = (cb + 0 == ii) ? 1.0f : 0.0f;
        o.y = (cb + 1 == ii) ? 1.0f : 0.0f;
        o.z = (cb + 2 == ii) ? 1.0f : 0.0f;
        o.w = (cb + 3 == ii) ? 1.0f : 0.0f;
        *(float4*)(dst + cb) = o;
    }
}

// ---------------------------------------------------------------------------
// K1c: fixup — recompute fragile rows with EXACT R6 numerics (serial-k fp32
// fmac chain, same q expression, global first-index ties), patch idx/onehot.
// Expected ~200-400 rows; one row per block, strided.
// ---------------------------------------------------------------------------
__global__ __launch_bounds__(256) void fixup_kernel(
        const float* __restrict__ z, const float* __restrict__ W,
        const float* __restrict__ se, const float* __restrict__ sz,
        const int* __restrict__ cnt, const int* __restrict__ list,
        int* __restrict__ idx_ws, float* __restrict__ out_idx,
        float* __restrict__ out_onehot) {
    __shared__ float zr[EDIM];
    __shared__ float rd[256];
    __shared__ int   ri[256];
    int n = *cnt; if (n > NROWS) n = NROWS;
    for (int f = blockIdx.x; f < n; f += gridDim.x) {
        const int row = list[f];
        __syncthreads();                       // protect zr across iterations
        const int b = row >> 13, sp = row & (SPAT - 1);
        zr[threadIdx.x] = z[(size_t)b * (EDIM * SPAT) + (size_t)threadIdx.x * SPAT + sp];
        __syncthreads();
        const float szr = sz[row];
        float best = 3.4e38f; int bi = 0;
        for (int c = threadIdx.x; c < N_E; c += 256) {
            float s = 0.f;
            const float* wr = W + (size_t)c * EDIM;
            for (int k = 0; k < EDIM; ++k) s += zr[k] * wr[k];   // serial k, fmac
            const float q = (szr + se[c]) - 2.0f * s;
            if (q < best) { best = q; bi = c; }
        }
        rd[threadIdx.x] = best; ri[threadIdx.x] = bi;
        __syncthreads();
        for (int off = 128; off > 0; off >>= 1) {
            if (threadIdx.x < off) {
                const float od = rd[threadIdx.x + off];
                const int oi = ri[threadIdx.x + off];
                if (od < rd[threadIdx.x] ||
                    (od == rd[threadIdx.x] && oi < ri[threadIdx.x])) {
                    rd[threadIdx.x] = od; ri[threadIdx.x] = oi;
                }
            }
            __syncthreads();
        }
        if (threadIdx.x == 0) {
            const int nw = ri[0], old = idx_ws[row];
            if (nw != old) {
                idx_ws[row] = nw;
                out_idx[row] = (float)nw;
                out_onehot[(size_t)row * N_E + old] = 0.f;
                out_onehot[(size_t)row * N_E + nw]  = 1.f;
            }
        }
        __syncthreads();
    }
}

// ---------------------------------------------------------------------------
// K2: z_q_out, z_out, loss partials (per-block slots) — unchanged from R6.
// ---------------------------------------------------------------------------
__global__ __launch_bounds__(256) void outputs_kernel(
        const float* __restrict__ z, const float* __restrict__ W,
        const int* __restrict__ idx,
        float* __restrict__ zq_out, float* __restrict__ z_out,
        double* __restrict__ loss_parts) {
    const int t  = blockIdx.x * 256 + threadIdx.x;
    const float zv = z[t];
    const int sp = t & (SPAT - 1);
    const int c  = (t >> 13) & 255;
    const int b  = t >> 21;
    const int n  = (b << 13) + sp;
    const int id = idx[n];
    const float e    = W[id * EDIM + c];
    const float diff = e - zv;
    zq_out[t] = zv + diff;
    z_out[t]  = zv;

    double ds = (double)(diff * diff);
    #pragma unroll
    for (int off = 32; off > 0; off >>= 1) ds += __shfl_down(ds, off);
    __shared__ double bsum[4];
    const int lane = threadIdx.x & 63, w = threadIdx.x >> 6;
    if (lane == 0) bsum[w] = ds;
    __syncthreads();
    if (threadIdx.x == 0)
        loss_parts[blockIdx.x] = bsum[0] + bsum[1] + bsum[2] + bsum[3];
}

// ---------------------------------------------------------------------------
// K3: EMA buffer update — unchanged.
// ---------------------------------------------------------------------------
__global__ __launch_bounds__(256) void ema_kernel(const float* __restrict__ W,
                                                  const float* __restrict__ ema,
                                                  float* __restrict__ out) {
    const int t = blockIdx.x * 256 + threadIdx.x;
    out[t] = 0.25f * ema[t] + 0.75f * W[t];
}

// ---------------------------------------------------------------------------
// K4: histogram + perplexity + loss finalize — unchanged.
// ---------------------------------------------------------------------------
__global__ __launch_bounds__(1024) void final_kernel(
        const int* __restrict__ idx, const double* __restrict__ loss_parts,
        float* __restrict__ out_loss, float* __restrict__ out_perp) {
    __shared__ int   hist[N_E];
    __shared__ float ps[1024];
    __shared__ double ls[1024];
    const int tid = threadIdx.x;

    for (int i = tid; i < N_E; i += 1024) hist[i] = 0;
    __syncthreads();
    for (int r = tid; r < NROWS; r += 1024) atomicAdd(&hist[idx[r]], 1);
    __syncthreads();

    float s = 0.f;
    for (int c = tid; c < N_E; c += 1024) {
        const float p = (float)hist[c] * (1.0f / (float)NROWS);
        s += p * logf(p + 1e-10f);
    }
    double l = 0.0;
    for (int c = tid; c < NLOSSPARTS; c += 1024) l += loss_parts[c];
    ps[tid] = s;
    ls[tid] = l;
    __syncthreads();
    for (int off = 512; off > 0; off >>= 1) {
        if (tid < off) {
            ps[tid] += ps[tid + off];
            ls[tid] += ls[tid + off];
        }
        __syncthreads();
    }
    if (tid == 0) {
        *out_perp = expf(-ps[0]);
        const float m = (float)(ls[0] / (double)ZELEMS);
        *out_loss = m + 0.25f * m;
    }
}

// ---------------------------------------------------------------------------
extern "C" void kernel_launch(void* const* d_in, const int* in_sizes, int n_in,
                              void* d_out, int out_size, void* d_ws, size_t ws_size,
                              hipStream_t stream) {
    const float* z   = (const float*)d_in[0];
    const float* W   = (const float*)d_in[1];
    const float* ema = (const float*)d_in[2];
    float* out = (float*)d_out;

    float* out_loss   = out + OFF_LOSS;
    float* out_zq     = out + OFF_ZQ;
    float* out_perp   = out + OFF_PERP;
    float* out_onehot = out + OFF_ONEHOT;
    float* out_idx    = out + OFF_IDX;
    float* out_z      = out + OFF_ZOUT;
    float* out_ema    = out + OFF_EMA;

    // scratch inside later-overwritten output regions
    u16* zh = (u16*)(out + SCR_ZH);
    u16* zl = (u16*)(out + SCR_ZL);
    u16* wh = (u16*)(out + SCR_WH);
    u16* wl = (u16*)(out + SCR_WL);
    float* bD = out + SCR_BD;
    int*   bI = (int*)(out + SCR_BI);

    // workspace (~340 KB, all rewritten each launch)
    char* ws = (char*)d_ws;
    float*  se    = (float*)ws;                   // 16 KB
    float*  sz    = (float*)(ws + 16384);         // 64 KB
    int*    idxb  = (int*)  (ws + 81920);         // 64 KB
    double* lossp = (double*)(ws + 147456);       // 128 KB
    int*    cnt   = (int*)  (ws + 278528);        // 4 B
    int*    list  = (int*)  (ws + 278532);        // 64 KB

    se_kernel<<<1024, 256, 0, stream>>>(W, se, cnt);
    rnorm_kernel<<<128, 512, 0, stream>>>(z, sz);
    split_w_kernel<<<1024, 256, 0, stream>>>(W, wh, wl);
    split_z_kernel<<<dim3(128, 2, 2), 256, 0, stream>>>(z, zh, zl);
    argmin_kernel<<<dim3(NCHUNK, NROWS / 128), 256, 0, stream>>>(zh, zl, wh, wl,
                                                                 se, sz, bD, bI);
    combine_kernel<<<NROWS / 4, 256, 0, stream>>>(bD, bI, idxb, out_idx,
                                                  out_onehot, cnt, list);
    fixup_kernel<<<256, 256, 0, stream>>>(z, W, se, sz, cnt, list, idxb,
                                          out_idx, out_onehot);
    outputs_kernel<<<ZELEMS / 256, 256, 0, stream>>>(z, W, idxb, out_zq, out_z,
                                                     lossp);
    ema_kernel<<<(N_E * EDIM) / 256, 256, 0, stream>>>(W, ema, out_ema);
    final_kernel<<<1, 1024, 0, stream>>>(idxb, lossp, out_loss, out_perp);
}

// Round 2
// 761.053 us; speedup vs baseline: 11.0390x; 11.0390x over previous
//
#include <hip/hip_runtime.h>
#include <math.h>

// ---------------------------------------------------------------------------
// VectorQuantizer3D — R10: bf16-split MFMA argmin (R9) kept; the buggy
// fragility-flag + brute-force fixup (7.8 ms: flag gated on RUNNING min ->
// every row flagged) is replaced by a sound candidate-chunk resolve:
// MFMA chunk-minima select ~1.1 chunks/row; only those 128-code chunks are
// recomputed with the R6-exact serial-k fp32 numerics (hardware-validated
// reference-exact by R9's accidental full-coverage run). One-hot write fused.
// ---------------------------------------------------------------------------

#define N_E    4096
#define EDIM   256
#define SPAT   8192
#define NROWS  16384
#define ZELEMS 4194304
#define NCHUNK 32        // code chunks of 128
#define NLOSSPARTS 16384

// Output offsets (flat float32 in return order)
#define OFF_LOSS    0
#define OFF_ZQ      1
#define OFF_PERP    4194305
#define OFF_ONEHOT  4194306
#define OFF_IDX     71303170
#define OFF_ZOUT    71319554
#define OFF_EMA     75513858

// Scratch carved out of output regions that are fully rewritten later:
//  - zh/zl/wh/wl live in out_onehot (resolve_kernel rewrites every row after
//    argmin_kernel is done reading them).
//  - bD/bI partials live in out_z (outputs_kernel rewrites it after resolve).
#define SCR_ZH  4194308
#define SCR_ZL  6291460
#define SCR_WH  8388612
#define SCR_WL  8912900
#define SCR_BD  71319554
#define SCR_BI  71843842

// Candidate margin: any R6-winner satisfies q_mfma <= gmin + 2*ulp(~3e-5)
// given split error << half-ulp; 1.5e-4 is ~2.4x conservative.
#define MARG 1.5e-4f

typedef unsigned short u16;
typedef short short8 __attribute__((ext_vector_type(8)));
typedef float f32x4 __attribute__((ext_vector_type(4)));
typedef const void __attribute__((address_space(1)))* gas1;
typedef void __attribute__((address_space(3)))* las3;
#define GLOAD16(g, l) __builtin_amdgcn_global_load_lds((gas1)(g), (las3)(l), 16, 0, 0)

__device__ __forceinline__ u16 f2bf(float f) {   // RTNE fp32 -> bf16
    unsigned u = __float_as_uint(f);
    return (u16)((u + 0x7fffu + ((u >> 16) & 1u)) >> 16);
}
__device__ __forceinline__ float bf2f(u16 h) {
    return __uint_as_float(((unsigned)h) << 16);
}

// ---------------------------------------------------------------------------
// K0a: se[c] = sum_k W[c][k]^2 — VERBATIM R6 numerics (resolve bit-matches).
// ---------------------------------------------------------------------------
__global__ __launch_bounds__(256) void se_kernel(const float* __restrict__ W,
                                                 float* __restrict__ se) {
    int wid  = (blockIdx.x * 256 + threadIdx.x) >> 6;
    int lane = threadIdx.x & 63;
    if (wid < N_E) {
        const float4 v = *(const float4*)(W + (size_t)wid * EDIM + lane * 4);
        float s = v.x * v.x + v.y * v.y + v.z * v.z + v.w * v.w;
        #pragma unroll
        for (int off = 32; off > 0; off >>= 1) s += __shfl_down(s, off);
        if (lane == 0) se[wid] = s;
    }
}

// ---------------------------------------------------------------------------
// K0b: sz[row] = ||z_row||^2 — R6's exact summation order.
// ---------------------------------------------------------------------------
__global__ __launch_bounds__(512) void rnorm_kernel(const float* __restrict__ z,
                                                    float* __restrict__ sz) {
    const int r0 = blockIdx.x * 128;
    const int bb = r0 >> 13;
    const int sp0 = r0 & (SPAT - 1);
    const float* zb = z + (size_t)bb * (EDIM * SPAT) + sp0;
    __shared__ float szp[4][128];
    const int lr = threadIdx.x & 127, kq = threadIdx.x >> 7;
    float s = 0.f;
    const float* p = zb + lr + (size_t)(kq * 64) * SPAT;
    for (int k = 0; k < 64; ++k) {
        float v = p[(size_t)k * SPAT];
        s += v * v;
    }
    szp[kq][lr] = s;
    __syncthreads();
    if (threadIdx.x < 128)
        sz[r0 + threadIdx.x] =
            ((szp[0][threadIdx.x] + szp[1][threadIdx.x]) + szp[2][threadIdx.x]) + szp[3][threadIdx.x];
}

// ---------------------------------------------------------------------------
// K0c: W -> bf16 hi/lo split, row-major [4096][256].
// ---------------------------------------------------------------------------
__global__ __launch_bounds__(256) void split_w_kernel(const float* __restrict__ W,
                                                      u16* __restrict__ wh,
                                                      u16* __restrict__ wl) {
    const size_t t = (size_t)blockIdx.x * 256 + threadIdx.x;   // 0..262143
    const float4 v = *(const float4*)(W + t * 4);
    u16 h0 = f2bf(v.x), h1 = f2bf(v.y), h2 = f2bf(v.z), h3 = f2bf(v.w);
    u16 l0 = f2bf(v.x - bf2f(h0)), l1 = f2bf(v.y - bf2f(h1));
    u16 l2 = f2bf(v.z - bf2f(h2)), l3 = f2bf(v.w - bf2f(h3));
    uint2 hp, lp;
    hp.x = (unsigned)h0 | ((unsigned)h1 << 16); hp.y = (unsigned)h2 | ((unsigned)h3 << 16);
    lp.x = (unsigned)l0 | ((unsigned)l1 << 16); lp.y = (unsigned)l2 | ((unsigned)l3 << 16);
    *(uint2*)(wh + t * 4) = hp;
    *(uint2*)(wl + t * 4) = lp;
}

// ---------------------------------------------------------------------------
// K0d: z [2][256][8192] -> transposed bf16 hi/lo [16384 rows][256 k].
// ---------------------------------------------------------------------------
__global__ __launch_bounds__(256) void split_z_kernel(const float* __restrict__ z,
                                                      u16* __restrict__ zh,
                                                      u16* __restrict__ zl) {
    __shared__ float t[128][65];
    const int tid = threadIdx.x, wid = tid >> 6, lane = tid & 63;
    const int sp0 = blockIdx.x * 64, c0 = blockIdx.y * 128, b = blockIdx.z;
    const float* zb = z + (size_t)b * (EDIM * SPAT);
    #pragma unroll
    for (int it = 0; it < 32; ++it) {
        const int cl = wid + 4 * it;                 // 0..127
        t[cl][lane] = zb[(size_t)(c0 + cl) * SPAT + sp0 + lane];
    }
    __syncthreads();
    #pragma unroll
    for (int it = 0; it < 16; ++it) {
        const int r = wid + 4 * it;                  // 0..63
        const float v0 = t[2 * lane][r], v1 = t[2 * lane + 1][r];
        const u16 h0 = f2bf(v0), h1 = f2bf(v1);
        const u16 l0 = f2bf(v0 - bf2f(h0)), l1 = f2bf(v1 - bf2f(h1));
        const size_t row = (size_t)b * SPAT + sp0 + r;
        ((unsigned*)zh)[row * 128 + (c0 >> 1) + lane] = (unsigned)h0 | ((unsigned)h1 << 16);
        ((unsigned*)zl)[row * 128 + (c0 >> 1) + lane] = (unsigned)l0 | ((unsigned)l1 << 16);
    }
}

// ---------------------------------------------------------------------------
// K1: MFMA argmin. 128 rows x 128 codes per block, BK=32, 4 waves (2Mx2N),
// wave tile 64x64 = 4x4 16x16x32 frags, 3 MFMAs per frag (zh*wh+zh*wl+zl*wh).
// Epilogue: quantized q = (szr+se) - 2*acc, per-chunk first-index argmin only
// (fragility machinery removed — resolve_kernel handles exactness).
// ---------------------------------------------------------------------------
__global__ __launch_bounds__(256, 3) void argmin_kernel(
        const u16* __restrict__ zh, const u16* __restrict__ zl,
        const u16* __restrict__ wh, const u16* __restrict__ wl,
        const float* __restrict__ se, const float* __restrict__ sz,
        float* __restrict__ bD, int* __restrict__ bI) {
    __shared__ u16 sW[128][64];     // 16 KB: [code][hi32|lo32]
    __shared__ u16 sZ[128][64];     // 16 KB: [row ][hi32|lo32]
    __shared__ float mD[2][128];
    __shared__ int   mI[2][128];

    const int tid = threadIdx.x;
    const int wid = tid >> 6, lane = tid & 63;
    const int wm = wid >> 1, wn = wid & 1;
    const int lq = lane >> 4, lr = lane & 15;
    const int chunk = blockIdx.x;          // 0..31
    const int rbase = blockIdx.y * 128;
    const int cbase = chunk * 128;

    // staging: 2048 16-B chunks (1024 sW + 1024 sZ), 8 per thread.
    // LDS chunk o -> (row=o>>3, pos g=o&7); data there must be unswizzled
    // chunk u = g ^ (row&7); u<4 -> hi, else lo; k-offset (u&3)*8.
    const u16* gw[4]; const u16* gz[4];
    #pragma unroll
    for (int i = 0; i < 4; ++i) {
        const int o = i * 256 + tid;
        const int row = o >> 3, g = o & 7, u = g ^ (row & 7);
        const int ks = (u & 3) * 8;
        gw[i] = (u < 4 ? wh : wl) + (size_t)(cbase + row) * EDIM + ks;
        gz[i] = (u < 4 ? zh : zl) + (size_t)(rbase + row) * EDIM + ks;
    }

    // fragment LDS byte offsets (stage-invariant): row*128 + swz_chunk*16
    int aoff[4][2], boff[4][2];
    #pragma unroll
    for (int tt = 0; tt < 4; ++tt) {
        const int cl = wn * 64 + tt * 16 + lr;
        const int s0 = lq ^ (cl & 7);
        aoff[tt][0] = cl * 128 + s0 * 16;
        aoff[tt][1] = cl * 128 + (s0 ^ 4) * 16;
        const int rl = wm * 64 + tt * 16 + lr;
        const int s1 = lq ^ (rl & 7);
        boff[tt][0] = rl * 128 + s1 * 16;
        boff[tt][1] = rl * 128 + (s1 ^ 4) * 16;
    }

    f32x4 acc[4][4];
    #pragma unroll
    for (int ci = 0; ci < 4; ++ci)
        #pragma unroll
        for (int rj = 0; rj < 4; ++rj) {
            f32x4 zzz = {0.f, 0.f, 0.f, 0.f};
            acc[ci][rj] = zzz;
        }

    const char* sWb = (const char*)&sW[0][0];
    const char* sZb = (const char*)&sZ[0][0];

    for (int k0 = 0; k0 < 8; ++k0) {
        __syncthreads();                               // prev frag reads done
        #pragma unroll
        for (int i = 0; i < 4; ++i) {
            GLOAD16(gw[i], (char*)&sW[0][0] + (i * 256 + wid * 64) * 16);
            GLOAD16(gz[i], (char*)&sZ[0][0] + (i * 256 + wid * 64) * 16);
            gw[i] += 32; gz[i] += 32;
        }
        __syncthreads();                               // vmcnt(0) drain -> LDS valid

        short8 zbh[4], zbl[4];
        #pragma unroll
        for (int rj = 0; rj < 4; ++rj) {
            zbh[rj] = *(const short8*)(sZb + boff[rj][0]);
            zbl[rj] = *(const short8*)(sZb + boff[rj][1]);
        }
        #pragma unroll
        for (int ci = 0; ci < 4; ++ci) {
            const short8 wah = *(const short8*)(sWb + aoff[ci][0]);
            const short8 wal = *(const short8*)(sWb + aoff[ci][1]);
            #pragma unroll
            for (int rj = 0; rj < 4; ++rj) {
                acc[ci][rj] = __builtin_amdgcn_mfma_f32_16x16x32_bf16(wah, zbh[rj], acc[ci][rj], 0, 0, 0);
                acc[ci][rj] = __builtin_amdgcn_mfma_f32_16x16x32_bf16(wah, zbl[rj], acc[ci][rj], 0, 0, 0);
                acc[ci][rj] = __builtin_amdgcn_mfma_f32_16x16x32_bf16(wal, zbh[rj], acc[ci][rj], 0, 0, 0);
            }
        }
    }

    // ---- epilogue: per-chunk quantized first-index argmin ----
    f32x4 sev[4];
    #pragma unroll
    for (int ci = 0; ci < 4; ++ci)
        sev[ci] = *(const f32x4*)(se + cbase + wn * 64 + ci * 16 + lq * 4);

    #pragma unroll
    for (int rj = 0; rj < 4; ++rj) {
        const int rloc = wm * 64 + rj * 16 + lr;
        const float szr = sz[rbase + rloc];
        float b1 = 3.4e38f; int bi1 = 0x7fffffff;
        #pragma unroll
        for (int ci = 0; ci < 4; ++ci) {
            #pragma unroll
            for (int r = 0; r < 4; ++r) {
                const float q = (szr + sev[ci][r]) - 2.0f * acc[ci][rj][r];
                const int code = cbase + wn * 64 + ci * 16 + lq * 4 + r;
                if (q < b1 || (q == b1 && code < bi1)) { b1 = q; bi1 = code; }
            }
        }
        #pragma unroll
        for (int mask = 16; mask <= 32; mask <<= 1) {
            const float od = __shfl_xor(b1, mask);
            const int   oi = __shfl_xor(bi1, mask);
            if (od < b1 || (od == b1 && oi < bi1)) { b1 = od; bi1 = oi; }
        }
        if (lq == 0) {
            mD[wn][rloc] = b1;
            mI[wn][rloc] = bi1;
        }
    }
    __syncthreads();
    if (tid < 128) {
        const float d0 = mD[0][tid], d1 = mD[1][tid];
        const int i0 = mI[0][tid], i1 = mI[1][tid];
        float dm; int im;
        if (d1 < d0 || (d1 == d0 && i1 < i0)) { dm = d1; im = i1; }
        else                                  { dm = d0; im = i0; }
        bD[(size_t)chunk * NROWS + rbase + tid] = dm;
        bI[(size_t)chunk * NROWS + rbase + tid] = im;
    }
}

// ---------------------------------------------------------------------------
// K1b: resolve — block per row. Combine 32 MFMA chunk-minima -> global min;
// select chunks within MARG; recompute ONLY those chunks' codes with the
// R6-exact serial-k fp32 numerics (validated reference-exact in R9's run);
// first-index ties. Fuses the one-hot row write (zeros issued early so the
// stores drain under the rescan; single 1.0 patched at the end).
// Soundness: any code c with q_r6(c) <= min_r6 has q_mfma(c) <= gmin + 2ulp
// (split error << half-ulp), so candidate chunks cover every possible winner;
// non-candidates can never win.
// ---------------------------------------------------------------------------
__global__ __launch_bounds__(256) void resolve_kernel(
        const float* __restrict__ z, const float* __restrict__ W,
        const float* __restrict__ se, const float* __restrict__ sz,
        const float* __restrict__ bD, const int* __restrict__ bI,
        int* __restrict__ idx_ws, float* __restrict__ out_idx,
        float* __restrict__ out_onehot) {
    __shared__ float zr[EDIM];
    __shared__ float rd[128];
    __shared__ int   ri[128];
    __shared__ unsigned smask;
    const int row = blockIdx.x;
    const int tid = threadIdx.x;
    const int b = row >> 13, sp = row & (SPAT - 1);

    // (a) combine chunk minima (wave 0; lanes 32-63 duplicate lanes 0-31)
    if (tid < 64) {
        const int c = tid & 31;
        float d = bD[(size_t)c * NROWS + row];
        float dmin = d;
        #pragma unroll
        for (int mask = 16; mask > 0; mask >>= 1)
            dmin = fminf(dmin, __shfl_xor(dmin, mask));
        unsigned long long m = __ballot(d <= dmin + MARG);
        if (tid == 0) smask = (unsigned)(m & 0xffffffffu);
    }
    // (b) zero the one-hot row early — stores drain during the rescan
    float* dst = out_onehot + (size_t)row * N_E;
    {
        const float4 z4 = {0.f, 0.f, 0.f, 0.f};
        #pragma unroll
        for (int w = 0; w < 4; ++w)
            *(float4*)(dst + w * 1024 + tid * 4) = z4;
    }
    // (c) z row to LDS (R6 layout: zr[k] = z[b, k, sp])
    zr[tid] = z[(size_t)b * (EDIM * SPAT) + (size_t)tid * SPAT + sp];
    __syncthreads();

    // (d) exact rescan of candidate chunks (ascending chunk order)
    const float szr = sz[row];
    unsigned cmask = smask;
    float best = 3.4e38f; int bi = 0x7fffffff;
    while (cmask) {
        const int cc = __ffs(cmask) - 1;
        cmask &= cmask - 1;
        if (tid < 128) {
            const int code = cc * 128 + tid;
            const float* wr = W + (size_t)code * EDIM;
            float s = 0.f;
            for (int k = 0; k < EDIM; ++k) s += zr[k] * wr[k];   // serial k
            const float q = (szr + se[code]) - 2.0f * s;
            if (q < best || (q == best && code < bi)) { best = q; bi = code; }
        }
    }
    if (tid < 128) { rd[tid] = best; ri[tid] = bi; }
    __syncthreads();
    for (int off = 64; off > 0; off >>= 1) {
        if (tid < off) {
            const float od = rd[tid + off]; const int oi = ri[tid + off];
            if (od < rd[tid] || (od == rd[tid] && oi < ri[tid])) {
                rd[tid] = od; ri[tid] = oi;
            }
        }
        __syncthreads();
    }
    if (tid == 0) {
        const int ii = ri[0];
        idx_ws[row]  = ii;
        out_idx[row] = (float)ii;
        dst[ii] = 1.0f;          // zeros completed at the barrier above
    }
}

// ---------------------------------------------------------------------------
// K2: z_q_out, z_out, loss partials — unchanged from R6.
// ---------------------------------------------------------------------------
__global__ __launch_bounds__(256) void outputs_kernel(
        const float* __restrict__ z, const float* __restrict__ W,
        const int* __restrict__ idx,
        float* __restrict__ zq_out, float* __restrict__ z_out,
        double* __restrict__ loss_parts) {
    const int t  = blockIdx.x * 256 + threadIdx.x;
    const float zv = z[t];
    const int sp = t & (SPAT - 1);
    const int c  = (t >> 13) & 255;
    const int b  = t >> 21;
    const int n  = (b << 13) + sp;
    const int id = idx[n];
    const float e    = W[id * EDIM + c];
    const float diff = e - zv;
    zq_out[t] = zv + diff;
    z_out[t]  = zv;

    double ds = (double)(diff * diff);
    #pragma unroll
    for (int off = 32; off > 0; off >>= 1) ds += __shfl_down(ds, off);
    __shared__ double bsum[4];
    const int lane = threadIdx.x & 63, w = threadIdx.x >> 6;
    if (lane == 0) bsum[w] = ds;
    __syncthreads();
    if (threadIdx.x == 0)
        loss_parts[blockIdx.x] = bsum[0] + bsum[1] + bsum[2] + bsum[3];
}

// ---------------------------------------------------------------------------
// K3: EMA buffer update — unchanged.
// ---------------------------------------------------------------------------
__global__ __launch_bounds__(256) void ema_kernel(const float* __restrict__ W,
                                                  const float* __restrict__ ema,
                                                  float* __restrict__ out) {
    const int t = blockIdx.x * 256 + threadIdx.x;
    out[t] = 0.25f * ema[t] + 0.75f * W[t];
}

// ---------------------------------------------------------------------------
// K4: histogram + perplexity + loss finalize — unchanged.
// ---------------------------------------------------------------------------
__global__ __launch_bounds__(1024) void final_kernel(
        const int* __restrict__ idx, const double* __restrict__ loss_parts,
        float* __restrict__ out_loss, float* __restrict__ out_perp) {
    __shared__ int   hist[N_E];
    __shared__ float ps[1024];
    __shared__ double ls[1024];
    const int tid = threadIdx.x;

    for (int i = tid; i < N_E; i += 1024) hist[i] = 0;
    __syncthreads();
    for (int r = tid; r < NROWS; r += 1024) atomicAdd(&hist[idx[r]], 1);
    __syncthreads();

    float s = 0.f;
    for (int c = tid; c < N_E; c += 1024) {
        const float p = (float)hist[c] * (1.0f / (float)NROWS);
        s += p * logf(p + 1e-10f);
    }
    double l = 0.0;
    for (int c = tid; c < NLOSSPARTS; c += 1024) l += loss_parts[c];
    ps[tid] = s;
    ls[tid] = l;
    __syncthreads();
    for (int off = 512; off > 0; off >>= 1) {
        if (tid < off) {
            ps[tid] += ps[tid + off];
            ls[tid] += ls[tid + off];
        }
        __syncthreads();
    }
    if (tid == 0) {
        *out_perp = expf(-ps[0]);
        const float m = (float)(ls[0] / (double)ZELEMS);
        *out_loss = m + 0.25f * m;
    }
}

// ---------------------------------------------------------------------------
extern "C" void kernel_launch(void* const* d_in, const int* in_sizes, int n_in,
                              void* d_out, int out_size, void* d_ws, size_t ws_size,
                              hipStream_t stream) {
    const float* z   = (const float*)d_in[0];
    const float* W   = (const float*)d_in[1];
    const float* ema = (const float*)d_in[2];
    float* out = (float*)d_out;

    float* out_loss   = out + OFF_LOSS;
    float* out_zq     = out + OFF_ZQ;
    float* out_perp   = out + OFF_PERP;
    float* out_onehot = out + OFF_ONEHOT;
    float* out_idx    = out + OFF_IDX;
    float* out_z      = out + OFF_ZOUT;
    float* out_ema    = out + OFF_EMA;

    // scratch inside later-overwritten output regions
    u16* zh = (u16*)(out + SCR_ZH);
    u16* zl = (u16*)(out + SCR_ZL);
    u16* wh = (u16*)(out + SCR_WH);
    u16* wl = (u16*)(out + SCR_WL);
    float* bD = out + SCR_BD;
    int*   bI = (int*)(out + SCR_BI);

    // workspace
    char* ws = (char*)d_ws;
    float*  se    = (float*)ws;                   // 16 KB
    float*  sz    = (float*)(ws + 16384);         // 64 KB
    int*    idxb  = (int*)  (ws + 81920);         // 64 KB
    double* lossp = (double*)(ws + 147456);       // 128 KB

    se_kernel<<<1024, 256, 0, stream>>>(W, se);
    rnorm_kernel<<<128, 512, 0, stream>>>(z, sz);
    split_w_kernel<<<1024, 256, 0, stream>>>(W, wh, wl);
    split_z_kernel<<<dim3(128, 2, 2), 256, 0, stream>>>(z, zh, zl);
    argmin_kernel<<<dim3(NCHUNK, NROWS / 128), 256, 0, stream>>>(zh, zl, wh, wl,
                                                                 se, sz, bD, bI);
    resolve_kernel<<<NROWS, 256, 0, stream>>>(z, W, se, sz, bD, bI, idxb,
                                              out_idx, out_onehot);
    outputs_kernel<<<ZELEMS / 256, 256, 0, stream>>>(z, W, idxb, out_zq, out_z,
                                                     lossp);
    ema_kernel<<<(N_E * EDIM) / 256, 256, 0, stream>>>(W, ema, out_ema);
    final_kernel<<<1, 1024, 0, stream>>>(idxb, lossp, out_loss, out_perp);
}

// Round 3
// 566.479 us; speedup vs baseline: 14.8307x; 1.3435x over previous
//
#include <hip/hip_runtime.h>
#include <math.h>

// ---------------------------------------------------------------------------
// VectorQuantizer3D — R11: (1) one-hot zero-fill folded into argmin's store
// shadow (268 MB @ ~1.3 TB/s under MFMA); (2) per-chunk second-best tracking
// -> global top-2 gap test skips the exact rescan (and all z/W reads) when
// g2-g1 > 1.5e-4 (provably index-safe, same bound as validated MARG);
// (3) rescan path is R10's validated serial-k fp32 code, unchanged.
// Scratch re-layout frees the one-hot region during argmin.
// ---------------------------------------------------------------------------

#define N_E    4096
#define EDIM   256
#define SPAT   8192
#define NROWS  16384
#define ZELEMS 4194304
#define NCHUNK 32        // code chunks of 128
#define NLOSSPARTS 16384

// Output offsets (flat float32 in return order)
#define OFF_LOSS    0
#define OFF_ZQ      1
#define OFF_PERP    4194305
#define OFF_ONEHOT  4194306
#define OFF_IDX     71303170
#define OFF_ZOUT    71319554
#define OFF_EMA     75513858

// Scratch (float indices into out), all 16B-aligned, all in regions that are
// rewritten by outputs_kernel AFTER their last scratch read:
//   out_zq region [1, 4194305):      zl, wh, wl
//   out_z  region [71319554, 75513858): zh, bD, bI, bD2
#define SCR_ZL_F   4
#define SCR_WH_F   2097156
#define SCR_WL_F   2621444
#define SCR_ZH_F   71319556
#define SCR_BD_F   73416708
#define SCR_BI_F   73940996
#define SCR_BD2_F  74465284

// |q_mfma - q_r6| <= one ulp(256) quantizer step (~3.1e-5); 1.5e-4 = 2.4x
// margin — empirically validated by R10's absmax 0.0.
#define MARG 1.5e-4f
#define GAPM 1.5e-4f

typedef unsigned short u16;
typedef short short8 __attribute__((ext_vector_type(8)));
typedef float f32x4 __attribute__((ext_vector_type(4)));
typedef const void __attribute__((address_space(1)))* gas1;
typedef void __attribute__((address_space(3)))* las3;
#define GLOAD16(g, l) __builtin_amdgcn_global_load_lds((gas1)(g), (las3)(l), 16, 0, 0)

__device__ __forceinline__ u16 f2bf(float f) {   // RTNE fp32 -> bf16
    unsigned u = __float_as_uint(f);
    return (u16)((u + 0x7fffu + ((u >> 16) & 1u)) >> 16);
}
__device__ __forceinline__ float bf2f(u16 h) {
    return __uint_as_float(((unsigned)h) << 16);
}

// ---------------------------------------------------------------------------
// K0a: se[c] = sum_k W[c][k]^2 — VERBATIM R6 numerics.
// ---------------------------------------------------------------------------
__global__ __launch_bounds__(256) void se_kernel(const float* __restrict__ W,
                                                 float* __restrict__ se) {
    int wid  = (blockIdx.x * 256 + threadIdx.x) >> 6;
    int lane = threadIdx.x & 63;
    if (wid < N_E) {
        const float4 v = *(const float4*)(W + (size_t)wid * EDIM + lane * 4);
        float s = v.x * v.x + v.y * v.y + v.z * v.z + v.w * v.w;
        #pragma unroll
        for (int off = 32; off > 0; off >>= 1) s += __shfl_down(s, off);
        if (lane == 0) se[wid] = s;
    }
}

// ---------------------------------------------------------------------------
// K0b: sz[row] = ||z_row||^2 — R6's exact summation order.
// ---------------------------------------------------------------------------
__global__ __launch_bounds__(512) void rnorm_kernel(const float* __restrict__ z,
                                                    float* __restrict__ sz) {
    const int r0 = blockIdx.x * 128;
    const int bb = r0 >> 13;
    const int sp0 = r0 & (SPAT - 1);
    const float* zb = z + (size_t)bb * (EDIM * SPAT) + sp0;
    __shared__ float szp[4][128];
    const int lr = threadIdx.x & 127, kq = threadIdx.x >> 7;
    float s = 0.f;
    const float* p = zb + lr + (size_t)(kq * 64) * SPAT;
    for (int k = 0; k < 64; ++k) {
        float v = p[(size_t)k * SPAT];
        s += v * v;
    }
    szp[kq][lr] = s;
    __syncthreads();
    if (threadIdx.x < 128)
        sz[r0 + threadIdx.x] =
            ((szp[0][threadIdx.x] + szp[1][threadIdx.x]) + szp[2][threadIdx.x]) + szp[3][threadIdx.x];
}

// ---------------------------------------------------------------------------
// K0c: W -> bf16 hi/lo split, row-major [4096][256].
// ---------------------------------------------------------------------------
__global__ __launch_bounds__(256) void split_w_kernel(const float* __restrict__ W,
                                                      u16* __restrict__ wh,
                                                      u16* __restrict__ wl) {
    const size_t t = (size_t)blockIdx.x * 256 + threadIdx.x;   // 0..262143
    const float4 v = *(const float4*)(W + t * 4);
    u16 h0 = f2bf(v.x), h1 = f2bf(v.y), h2 = f2bf(v.z), h3 = f2bf(v.w);
    u16 l0 = f2bf(v.x - bf2f(h0)), l1 = f2bf(v.y - bf2f(h1));
    u16 l2 = f2bf(v.z - bf2f(h2)), l3 = f2bf(v.w - bf2f(h3));
    uint2 hp, lp;
    hp.x = (unsigned)h0 | ((unsigned)h1 << 16); hp.y = (unsigned)h2 | ((unsigned)h3 << 16);
    lp.x = (unsigned)l0 | ((unsigned)l1 << 16); lp.y = (unsigned)l2 | ((unsigned)l3 << 16);
    *(uint2*)(wh + t * 4) = hp;
    *(uint2*)(wl + t * 4) = lp;
}

// ---------------------------------------------------------------------------
// K0d: z [2][256][8192] -> transposed bf16 hi/lo [16384 rows][256 k].
// ---------------------------------------------------------------------------
__global__ __launch_bounds__(256) void split_z_kernel(const float* __restrict__ z,
                                                      u16* __restrict__ zh,
                                                      u16* __restrict__ zl) {
    __shared__ float t[128][65];
    const int tid = threadIdx.x, wid = tid >> 6, lane = tid & 63;
    const int sp0 = blockIdx.x * 64, c0 = blockIdx.y * 128, b = blockIdx.z;
    const float* zb = z + (size_t)b * (EDIM * SPAT);
    #pragma unroll
    for (int it = 0; it < 32; ++it) {
        const int cl = wid + 4 * it;                 // 0..127
        t[cl][lane] = zb[(size_t)(c0 + cl) * SPAT + sp0 + lane];
    }
    __syncthreads();
    #pragma unroll
    for (int it = 0; it < 16; ++it) {
        const int r = wid + 4 * it;                  // 0..63
        const float v0 = t[2 * lane][r], v1 = t[2 * lane + 1][r];
        const u16 h0 = f2bf(v0), h1 = f2bf(v1);
        const u16 l0 = f2bf(v0 - bf2f(h0)), l1 = f2bf(v1 - bf2f(h1));
        const size_t row = (size_t)b * SPAT + sp0 + r;
        ((unsigned*)zh)[row * 128 + (c0 >> 1) + lane] = (unsigned)h0 | ((unsigned)h1 << 16);
        ((unsigned*)zl)[row * 128 + (c0 >> 1) + lane] = (unsigned)l0 | ((unsigned)l1 << 16);
    }
}

// ---------------------------------------------------------------------------
// K1: MFMA argmin + per-chunk top-2 + one-hot zero slice.
// 128 rows x 128 codes per block, BK=32, 4 waves (2Mx2N), 3 MFMAs per frag.
// Epilogue tracks (best, idx, second-value); zero-fill of the block's 64 KB
// one-hot slice issued at the very end (drains under block exit / other waves).
// ---------------------------------------------------------------------------
__global__ __launch_bounds__(256, 3) void argmin_kernel(
        const u16* __restrict__ zh, const u16* __restrict__ zl,
        const u16* __restrict__ wh, const u16* __restrict__ wl,
        const float* __restrict__ se, const float* __restrict__ sz,
        float* __restrict__ bD, int* __restrict__ bI,
        float* __restrict__ bD2, float* __restrict__ out_onehot) {
    __shared__ u16 sW[128][64];     // 16 KB: [code][hi32|lo32]
    __shared__ u16 sZ[128][64];     // 16 KB: [row ][hi32|lo32]
    __shared__ float mD[2][128];
    __shared__ int   mI[2][128];
    __shared__ float mD2[2][128];

    const int tid = threadIdx.x;
    const int wid = tid >> 6, lane = tid & 63;
    const int wm = wid >> 1, wn = wid & 1;
    const int lq = lane >> 4, lr = lane & 15;
    const int chunk = blockIdx.x;          // 0..31
    const int rbase = blockIdx.y * 128;
    const int cbase = chunk * 128;

    // staging: 2048 16-B chunks (1024 sW + 1024 sZ), 8 per thread.
    // LDS chunk o -> (row=o>>3, pos g=o&7); data there must be unswizzled
    // chunk u = g ^ (row&7); u<4 -> hi, else lo; k-offset (u&3)*8.
    const u16* gw[4]; const u16* gz[4];
    #pragma unroll
    for (int i = 0; i < 4; ++i) {
        const int o = i * 256 + tid;
        const int row = o >> 3, g = o & 7, u = g ^ (row & 7);
        const int ks = (u & 3) * 8;
        gw[i] = (u < 4 ? wh : wl) + (size_t)(cbase + row) * EDIM + ks;
        gz[i] = (u < 4 ? zh : zl) + (size_t)(rbase + row) * EDIM + ks;
    }

    // fragment LDS byte offsets (stage-invariant): row*128 + swz_chunk*16
    int aoff[4][2], boff[4][2];
    #pragma unroll
    for (int tt = 0; tt < 4; ++tt) {
        const int cl = wn * 64 + tt * 16 + lr;
        const int s0 = lq ^ (cl & 7);
        aoff[tt][0] = cl * 128 + s0 * 16;
        aoff[tt][1] = cl * 128 + (s0 ^ 4) * 16;
        const int rl = wm * 64 + tt * 16 + lr;
        const int s1 = lq ^ (rl & 7);
        boff[tt][0] = rl * 128 + s1 * 16;
        boff[tt][1] = rl * 128 + (s1 ^ 4) * 16;
    }

    f32x4 acc[4][4];
    #pragma unroll
    for (int ci = 0; ci < 4; ++ci)
        #pragma unroll
        for (int rj = 0; rj < 4; ++rj) {
            f32x4 zzz = {0.f, 0.f, 0.f, 0.f};
            acc[ci][rj] = zzz;
        }

    const char* sWb = (const char*)&sW[0][0];
    const char* sZb = (const char*)&sZ[0][0];

    for (int k0 = 0; k0 < 8; ++k0) {
        __syncthreads();                               // prev frag reads done
        #pragma unroll
        for (int i = 0; i < 4; ++i) {
            GLOAD16(gw[i], (char*)&sW[0][0] + (i * 256 + wid * 64) * 16);
            GLOAD16(gz[i], (char*)&sZ[0][0] + (i * 256 + wid * 64) * 16);
            gw[i] += 32; gz[i] += 32;
        }
        __syncthreads();                               // vmcnt(0) drain -> LDS valid

        short8 zbh[4], zbl[4];
        #pragma unroll
        for (int rj = 0; rj < 4; ++rj) {
            zbh[rj] = *(const short8*)(sZb + boff[rj][0]);
            zbl[rj] = *(const short8*)(sZb + boff[rj][1]);
        }
        #pragma unroll
        for (int ci = 0; ci < 4; ++ci) {
            const short8 wah = *(const short8*)(sWb + aoff[ci][0]);
            const short8 wal = *(const short8*)(sWb + aoff[ci][1]);
            #pragma unroll
            for (int rj = 0; rj < 4; ++rj) {
                acc[ci][rj] = __builtin_amdgcn_mfma_f32_16x16x32_bf16(wah, zbh[rj], acc[ci][rj], 0, 0, 0);
                acc[ci][rj] = __builtin_amdgcn_mfma_f32_16x16x32_bf16(wah, zbl[rj], acc[ci][rj], 0, 0, 0);
                acc[ci][rj] = __builtin_amdgcn_mfma_f32_16x16x32_bf16(wal, zbh[rj], acc[ci][rj], 0, 0, 0);
            }
        }
    }

    // ---- epilogue: per-chunk quantized top-2 (value-only second) ----
    f32x4 sev[4];
    #pragma unroll
    for (int ci = 0; ci < 4; ++ci)
        sev[ci] = *(const f32x4*)(se + cbase + wn * 64 + ci * 16 + lq * 4);

    #pragma unroll
    for (int rj = 0; rj < 4; ++rj) {
        const int rloc = wm * 64 + rj * 16 + lr;
        const float szr = sz[rbase + rloc];
        float b1 = 3.4e38f, b2 = 3.4e38f; int bi1 = 0x7fffffff;
        #pragma unroll
        for (int ci = 0; ci < 4; ++ci) {
            #pragma unroll
            for (int r = 0; r < 4; ++r) {
                const float q = (szr + sev[ci][r]) - 2.0f * acc[ci][rj][r];
                const int code = cbase + wn * 64 + ci * 16 + lq * 4 + r;
                if (q < b1 || (q == b1 && code < bi1)) {
                    b2 = b1; b1 = q; bi1 = code;
                } else if (q < b2) {
                    b2 = q;
                }
            }
        }
        #pragma unroll
        for (int mask = 16; mask <= 32; mask <<= 1) {
            const float od1 = __shfl_xor(b1, mask);
            const int   oi1 = __shfl_xor(bi1, mask);
            const float od2 = __shfl_xor(b2, mask);
            const bool ot = (od1 < b1) || (od1 == b1 && oi1 < bi1);
            if (ot) { b2 = fminf(b1, od2); b1 = od1; bi1 = oi1; }
            else    { b2 = fminf(b2, od1); }
        }
        if (lq == 0) {
            mD[wn][rloc]  = b1;
            mI[wn][rloc]  = bi1;
            mD2[wn][rloc] = b2;
        }
    }
    __syncthreads();
    if (tid < 128) {
        const float d0 = mD[0][tid], d1 = mD[1][tid];
        const int   i0 = mI[0][tid], i1 = mI[1][tid];
        const float s0 = mD2[0][tid], s1 = mD2[1][tid];
        float dm, sm; int im;
        if (d1 < d0 || (d1 == d0 && i1 < i0)) { dm = d1; im = i1; sm = fminf(s1, d0); }
        else                                  { dm = d0; im = i0; sm = fminf(s0, d1); }
        bD [(size_t)chunk * NROWS + rbase + tid] = dm;
        bI [(size_t)chunk * NROWS + rbase + tid] = im;
        bD2[(size_t)chunk * NROWS + rbase + tid] = sm;
    }

    // ---- one-hot zero slice (64 KB per block; drains under block exit) ----
    {
        const int slice = blockIdx.y * 32 + blockIdx.x;   // 0..4095
        float* oh = out_onehot + (size_t)slice * 16384;
        const float4 z4 = {0.f, 0.f, 0.f, 0.f};
        #pragma unroll
        for (int it = 0; it < 16; ++it)
            *(float4*)(oh + it * 1024 + tid * 4) = z4;
    }
}

// ---------------------------------------------------------------------------
// K1b: resolve — block per row. Global top-2 from per-chunk (top1, top2).
// Fast path (g2-g1 > GAPM): accept MFMA winner, patch one-hot, done — no z/W.
// Slow path: R10's validated exact serial-k rescan of candidate chunks.
// ---------------------------------------------------------------------------
__global__ __launch_bounds__(256) void resolve_kernel(
        const float* __restrict__ z, const float* __restrict__ W,
        const float* __restrict__ se, const float* __restrict__ sz,
        const float* __restrict__ bD, const int* __restrict__ bI,
        const float* __restrict__ bD2,
        int* __restrict__ idx_ws, float* __restrict__ out_idx,
        float* __restrict__ out_onehot) {
    __shared__ float zr[EDIM];
    __shared__ float rd[128];
    __shared__ int   ri[128];
    __shared__ unsigned smask;
    __shared__ int swin, sskip;
    const int row = blockIdx.x;
    const int tid = threadIdx.x;

    if (tid < 64) {
        const int c = tid & 31;
        const float d1 = bD [(size_t)c * NROWS + row];
        const int   i1 = bI [(size_t)c * NROWS + row];
        const float d2 = bD2[(size_t)c * NROWS + row];
        float b1 = d1, b2 = d2; int j1 = i1;
        #pragma unroll
        for (int mask = 16; mask > 0; mask >>= 1) {
            const float od1 = __shfl_xor(b1, mask);
            const int   oj1 = __shfl_xor(j1, mask);
            const float od2 = __shfl_xor(b2, mask);
            const bool ot = (od1 < b1) || (od1 == b1 && oj1 < j1);
            if (ot) { b2 = fminf(b1, od2); b1 = od1; j1 = oj1; }
            else    { b2 = fminf(b2, od1); }
        }
        const unsigned long long m = __ballot(d1 <= b1 + MARG);
        if (tid == 0) {
            smask = (unsigned)(m & 0xffffffffu);
            swin  = j1;
            sskip = (b2 - b1 > GAPM) ? 1 : 0;
        }
    }
    __syncthreads();

    if (sskip) {
        if (tid == 0) {
            idx_ws[row]  = swin;
            out_idx[row] = (float)swin;
            out_onehot[(size_t)row * N_E + swin] = 1.0f;
        }
        return;
    }

    // slow path: exact rescan (R10-validated numerics, unchanged)
    const int b = row >> 13, sp = row & (SPAT - 1);
    zr[tid] = z[(size_t)b * (EDIM * SPAT) + (size_t)tid * SPAT + sp];
    __syncthreads();

    const float szr = sz[row];
    unsigned cmask = smask;
    float best = 3.4e38f; int bi = 0x7fffffff;
    while (cmask) {
        const int cc = __ffs(cmask) - 1;
        cmask &= cmask - 1;
        if (tid < 128) {
            const int code = cc * 128 + tid;
            const float* wr = W + (size_t)code * EDIM;
            float s = 0.f;
            for (int k = 0; k < EDIM; ++k) s += zr[k] * wr[k];   // serial k
            const float q = (szr + se[code]) - 2.0f * s;
            if (q < best || (q == best && code < bi)) { best = q; bi = code; }
        }
    }
    if (tid < 128) { rd[tid] = best; ri[tid] = bi; }
    __syncthreads();
    for (int off = 64; off > 0; off >>= 1) {
        if (tid < off) {
            const float od = rd[tid + off]; const int oi = ri[tid + off];
            if (od < rd[tid] || (od == rd[tid] && oi < ri[tid])) {
                rd[tid] = od; ri[tid] = oi;
            }
        }
        __syncthreads();
    }
    if (tid == 0) {
        const int ii = ri[0];
        idx_ws[row]  = ii;
        out_idx[row] = (float)ii;
        out_onehot[(size_t)row * N_E + ii] = 1.0f;
    }
}

// ---------------------------------------------------------------------------
// K2: z_q_out, z_out, loss partials — unchanged from R6.
// ---------------------------------------------------------------------------
__global__ __launch_bounds__(256) void outputs_kernel(
        const float* __restrict__ z, const float* __restrict__ W,
        const int* __restrict__ idx,
        float* __restrict__ zq_out, float* __restrict__ z_out,
        double* __restrict__ loss_parts) {
    const int t  = blockIdx.x * 256 + threadIdx.x;
    const float zv = z[t];
    const int sp = t & (SPAT - 1);
    const int c  = (t >> 13) & 255;
    const int b  = t >> 21;
    const int n  = (b << 13) + sp;
    const int id = idx[n];
    const float e    = W[id * EDIM + c];
    const float diff = e - zv;
    zq_out[t] = zv + diff;
    z_out[t]  = zv;

    double ds = (double)(diff * diff);
    #pragma unroll
    for (int off = 32; off > 0; off >>= 1) ds += __shfl_down(ds, off);
    __shared__ double bsum[4];
    const int lane = threadIdx.x & 63, w = threadIdx.x >> 6;
    if (lane == 0) bsum[w] = ds;
    __syncthreads();
    if (threadIdx.x == 0)
        loss_parts[blockIdx.x] = bsum[0] + bsum[1] + bsum[2] + bsum[3];
}

// ---------------------------------------------------------------------------
// K3: EMA buffer update — unchanged.
// ---------------------------------------------------------------------------
__global__ __launch_bounds__(256) void ema_kernel(const float* __restrict__ W,
                                                  const float* __restrict__ ema,
                                                  float* __restrict__ out) {
    const int t = blockIdx.x * 256 + threadIdx.x;
    out[t] = 0.25f * ema[t] + 0.75f * W[t];
}

// ---------------------------------------------------------------------------
// K4: histogram + perplexity + loss finalize — unchanged.
// ---------------------------------------------------------------------------
__global__ __launch_bounds__(1024) void final_kernel(
        const int* __restrict__ idx, const double* __restrict__ loss_parts,
        float* __restrict__ out_loss, float* __restrict__ out_perp) {
    __shared__ int   hist[N_E];
    __shared__ float ps[1024];
    __shared__ double ls[1024];
    const int tid = threadIdx.x;

    for (int i = tid; i < N_E; i += 1024) hist[i] = 0;
    __syncthreads();
    for (int r = tid; r < NROWS; r += 1024) atomicAdd(&hist[idx[r]], 1);
    __syncthreads();

    float s = 0.f;
    for (int c = tid; c < N_E; c += 1024) {
        const float p = (float)hist[c] * (1.0f / (float)NROWS);
        s += p * logf(p + 1e-10f);
    }
    double l = 0.0;
    for (int c = tid; c < NLOSSPARTS; c += 1024) l += loss_parts[c];
    ps[tid] = s;
    ls[tid] = l;
    __syncthreads();
    for (int off = 512; off > 0; off >>= 1) {
        if (tid < off) {
            ps[tid] += ps[tid + off];
            ls[tid] += ls[tid + off];
        }
        __syncthreads();
    }
    if (tid == 0) {
        *out_perp = expf(-ps[0]);
        const float m = (float)(ls[0] / (double)ZELEMS);
        *out_loss = m + 0.25f * m;
    }
}

// ---------------------------------------------------------------------------
extern "C" void kernel_launch(void* const* d_in, const int* in_sizes, int n_in,
                              void* d_out, int out_size, void* d_ws, size_t ws_size,
                              hipStream_t stream) {
    const float* z   = (const float*)d_in[0];
    const float* W   = (const float*)d_in[1];
    const float* ema = (const float*)d_in[2];
    float* out = (float*)d_out;

    float* out_loss   = out + OFF_LOSS;
    float* out_zq     = out + OFF_ZQ;
    float* out_perp   = out + OFF_PERP;
    float* out_onehot = out + OFF_ONEHOT;
    float* out_idx    = out + OFF_IDX;
    float* out_z      = out + OFF_ZOUT;
    float* out_ema    = out + OFF_EMA;

    // scratch inside later-overwritten output regions (16B-aligned)
    u16*   zl  = (u16*)(out + SCR_ZL_F);
    u16*   wh  = (u16*)(out + SCR_WH_F);
    u16*   wl  = (u16*)(out + SCR_WL_F);
    u16*   zh  = (u16*)(out + SCR_ZH_F);
    float* bD  = out + SCR_BD_F;
    int*   bI  = (int*)(out + SCR_BI_F);
    float* bD2 = out + SCR_BD2_F;

    // workspace
    char* ws = (char*)d_ws;
    float*  se    = (float*)ws;                   // 16 KB
    float*  sz    = (float*)(ws + 16384);         // 64 KB
    int*    idxb  = (int*)  (ws + 81920);         // 64 KB
    double* lossp = (double*)(ws + 147456);       // 128 KB

    se_kernel<<<1024, 256, 0, stream>>>(W, se);
    rnorm_kernel<<<128, 512, 0, stream>>>(z, sz);
    split_w_kernel<<<1024, 256, 0, stream>>>(W, wh, wl);
    split_z_kernel<<<dim3(128, 2, 2), 256, 0, stream>>>(z, zh, zl);
    argmin_kernel<<<dim3(NCHUNK, NROWS / 128), 256, 0, stream>>>(
        zh, zl, wh, wl, se, sz, bD, bI, bD2, out_onehot);
    resolve_kernel<<<NROWS, 256, 0, stream>>>(z, W, se, sz, bD, bI, bD2, idxb,
                                              out_idx, out_onehot);
    outputs_kernel<<<ZELEMS / 256, 256, 0, stream>>>(z, W, idxb, out_zq, out_z,
                                                     lossp);
    ema_kernel<<<(N_E * EDIM) / 256, 256, 0, stream>>>(W, ema, out_ema);
    final_kernel<<<1, 1024, 0, stream>>>(idxb, lossp, out_loss, out_perp);
}